// Round 19
// baseline (529.079 us; speedup 1.0000x reference)
//
#include <hip/hip_runtime.h>
#include <hip/hip_bf16.h>

// MSAColumnAttention fused kernels for MI355X (gfx950).
// N_SEQ=256, N_RES=256, D=256, H=8, C=32.
//
// ws layout (ushort elements):
//   [0       .. 196608)   qkv_wT  [768][256] bf16 (q rows pre-scaled by C^-0.5*log2e)
//   [196608  .. 262144)   gate_wT [256][256] bf16
//   [262144  .. 327680)   out_wT  [256][256] bf16
//   [327680  .. 17104896) og2     [r][h][s][c] bf16  (o * gate, head-major)
//   [17104896.. 33882112) Mn      [r][dt16][s][16] bf16 tiled (LayerNorm output)
//   [33882112.. 33898496) mbits   [r][hl][4] uint  (precomputed mask bitfields)

typedef short bf16x8 __attribute__((ext_vector_type(8)));
typedef float f32x4  __attribute__((ext_vector_type(4)));
typedef float f32x16 __attribute__((ext_vector_type(16)));

union U8 { uint w[4]; bf16x8 v; ushort u[8]; };

__device__ __forceinline__ ushort f2bf(float f) {
  uint u = __float_as_uint(f);
  u = (u + 0x7fffu + ((u >> 16) & 1u)) >> 16;   // RNE
  return (ushort)u;
}

// packed bf16 convert via library intrinsic -> compiler emits v_cvt_pk_bf16_f32
__device__ __forceinline__ uint pk2(float lo, float hi) {
  union { __hip_bfloat162 h; uint u; } cv;
  cv.h = __float22bfloat162_rn(float2{lo, hi});
  return cv.u;
}

// 2^x via v_exp_f32 (gfx950 v_exp_f32 computes 2^S0)
__device__ __forceinline__ float exp2fast(float x) {
  return __builtin_amdgcn_exp2f(x);
}

__device__ __forceinline__ f32x16 MFMA32(bf16x8 a, bf16x8 b, f32x16 c) {
  return __builtin_amdgcn_mfma_f32_32x32x16_bf16(a, b, c, 0, 0, 0);
}
__device__ __forceinline__ f32x4 MFMA16(bf16x8 a, bf16x8 b, f32x4 c) {
  return __builtin_amdgcn_mfma_f32_16x16x32_bf16(a, b, c, 0, 0, 0);
}

__device__ __forceinline__ bf16x8 ldG8(const ushort* __restrict__ p, int row, int ko) {
  return *(const bf16x8*)(p + (size_t)row * 256 + ko);
}

__device__ __forceinline__ f32x16 zero16() {
  f32x16 z;
  #pragma unroll
  for (int i = 0; i < 16; ++i) z[i] = 0.f;
  return z;
}

// ---------------- k_prep: weight transposes + mask bitfields -----------------
__global__ __launch_bounds__(256) void k_prep(const float* __restrict__ qkv_w,
                                              const float* __restrict__ gate_w,
                                              const float* __restrict__ out_w,
                                              const float* __restrict__ M_mask,
                                              ushort* __restrict__ ws,
                                              uint* __restrict__ mbits) {
  const int b = blockIdx.x;
  const int tid = threadIdx.x;
  if (b == 80) {
    const int r = tid;
    #pragma unroll
    for (int hl = 0; hl < 2; ++hl)
      #pragma unroll
      for (int j = 0; j < 4; ++j) {
        uint m = 0;
        for (int bb = 0; bb < 32; ++bb) {
          const int k0 = j*64 + ((bb>>4)<<5) + (bb&3) + (((bb>>2)&3)<<3) + hl*4;
          m |= (M_mask[(size_t)k0*256 + r] > 0.5f ? 1u : 0u) << bb;
        }
        mbits[(r*2 + hl)*4 + j] = m;
      }
    return;
  }
  __shared__ ushort t[64][72];
  const float* src; ushort* dst; int C, r0, c0; bool scale_q = false;
  if (b < 48)      { src = qkv_w;  dst = ws;          C = 768; r0 = (b/12)*64;      c0 = (b%12)*64; scale_q = true; }
  else if (b < 64) { int bb = b-48; src = gate_w; dst = ws + 196608; C = 256; r0 = (bb>>2)*64; c0 = (bb&3)*64; }
  else             { int bb = b-64; src = out_w;  dst = ws + 262144; C = 256; r0 = (bb>>2)*64; c0 = (bb&3)*64; }
  const int cc = tid & 63, rb = tid >> 6;
  #pragma unroll
  for (int j = 0; j < 16; ++j) {
    const int rr = j*4 + rb;
    float v = src[(size_t)(r0+rr)*C + c0 + cc];
    if (scale_q && (c0+cc) < 256) v *= 0.25503468786609404f;  // C^-0.5 * log2(e)
    t[cc][rr] = f2bf(v);
  }
  __syncthreads();
  const int dd = (tid & 31)*2, cb = tid >> 5;
  #pragma unroll
  for (int j = 0; j < 8; ++j) {
    const int c2 = j*8 + cb;
    const uint wv = (uint)t[c2][dd] | ((uint)t[c2][dd+1] << 16);
    *(uint*)(dst + (size_t)(c0+c2)*256 + r0 + dd) = wv;
  }
}

// ---------------- k_ln: LayerNorm -> Mn[r][dt][s][16] bf16 (tiled) -----------
__global__ __launch_bounds__(256) void k_ln(const float* __restrict__ M_raw,
                                            const float* __restrict__ ln_w,
                                            const float* __restrict__ ln_b,
                                            ushort* __restrict__ Mn) {
  const int s    = blockIdx.x;
  const int rc   = blockIdx.y;
  const int w    = threadIdx.x >> 6;
  const int lane = threadIdx.x & 63;
  const float4 wv = *(const float4*)(ln_w + lane*4);
  const float4 bv = *(const float4*)(ln_b + lane*4);
  const int wofs = (((lane >> 2) << 8) + s) * 16 + (lane & 3) * 4;
  #pragma unroll
  for (int i = 0; i < 8; ++i) {
    const int r = rc*32 + i*4 + w;
    const float4 x = *(const float4*)(M_raw + (size_t)s*65536 + (size_t)r*256 + lane*4);
    float sum = x.x + x.y + x.z + x.w;
    float sq  = x.x*x.x + x.y*x.y + x.z*x.z + x.w*x.w;
    #pragma unroll
    for (int mk = 1; mk <= 32; mk <<= 1) {
      sum += __shfl_xor(sum, mk, 64);
      sq  += __shfl_xor(sq,  mk, 64);
    }
    const float mu = sum * 0.00390625f;
    const float rs = rsqrtf(sq * 0.00390625f - mu*mu + 1e-5f);
    uint2 p2;
    p2.x = pk2((x.x-mu)*rs*wv.x+bv.x, (x.y-mu)*rs*wv.y+bv.y);
    p2.y = pk2((x.z-mu)*rs*wv.z+bv.z, (x.w-mu)*rs*wv.w+bv.w);
    *(uint2*)(Mn + (size_t)r*65536 + wofs) = p2;
  }
}

// ---------------- k_attn: one (r, head) per block, XCD-paired ----------------
// grid flat 2048: r = (bid>>6)*8 + (bid&7), h = (bid>>3)&7.
// (512,6): 85-reg cap -> 6 waves/SIMD -> 3 blocks/CU (LDS 3x53760 = 161KB fits).
// LDS (dynamic, 53760B):
//   K  [0,20480):      K[s 256][c 32] bf16, pitch 80B
//   VT [20480,37376):  VT[c 32][s 256] bf16, pitch 528B
//   OG [37376,53760):  og [s 256][cpair 16] uint, XOR swz
#define KOFF 0
#define VOFF 20480
#define GOFF 37376

__global__ __launch_bounds__(512, 6) void k_attn(
    const ushort* __restrict__ Mn, const uint* __restrict__ mbits,
    const ushort* __restrict__ qkv_wT, const ushort* __restrict__ gate_wT,
    const float* __restrict__ gate_b, ushort* __restrict__ og)
{
  extern __shared__ char smem[];
  const int bid  = blockIdx.x;
  const int r    = ((bid >> 6) << 3) | (bid & 7);
  const int hd   = (bid >> 3) & 7;
  const int hs   = hd << 5;
  const int tid  = threadIdx.x;
  const int w    = tid >> 6;
  const int lane = tid & 63;
  const int l31  = lane & 31;
  const int hl   = lane >> 5;          // half-wave 0/1
  const int Q0   = w << 5;             // this wave's 32 s-rows
  const int s    = Q0 + l31;           // this lane's s-row (= its q column)
  const ushort* __restrict__ MnR = Mn + (size_t)r * 65536;

  auto ldMnT = [&](int dt) -> bf16x8 {
    return *(const bf16x8*)(MnR + ((dt << 8) + s) * 16 + hl * 8);
  };

  const uint4 mw4 = *(const uint4*)(mbits + (r*2 + hl)*4);
  const uint m0 = mw4.x, m1 = mw4.y, m2 = mw4.z, m3 = mw4.w;
  const bool full = ((m0 & m1 & m2 & m3) == 0xFFFFFFFFu);

  // C-frag (col=l31) -> A/B operand frag via shfl_xor 32 + select (proven r6..r18)
  auto mergeOp = [&](float q0, float q1, float q2, float q3,
                     float q4, float q5, float q6, float q7) -> bf16x8 {
    const uint x0 = pk2(q0, q1), x1 = pk2(q2, q3);
    const uint z0 = pk2(q4, q5), z1 = pk2(q6, q7);
    const uint xx0 = __shfl_xor(x0, 32, 64), xx1 = __shfl_xor(x1, 32, 64);
    const uint zz0 = __shfl_xor(z0, 32, 64), zz1 = __shfl_xor(z1, 32, 64);
    U8 u;
    u.w[0] = hl ? zz0 : x0;
    u.w[1] = hl ? zz1 : x1;
    u.w[2] = hl ? z0  : xx0;
    u.w[3] = hl ? z1  : xx1;
    return u.v;
  };

  // projT: C[row=c-local][col=s=l31] = W^T @ Mn^T   (single acc: min liveness)
  auto projT = [&](const ushort* __restrict__ W, int rowbase) -> f32x16 {
    f32x16 a0 = zero16();
    #pragma unroll
    for (int dt = 0; dt < 16; ++dt)
      a0 = MFMA32(ldG8(W, rowbase + l31, dt*16 + hl*8), ldMnT(dt), a0);
    return a0;
  };
  // projN: C[row=s-local][col=c=l31] = Mn @ W   (single acc)
  auto projN = [&](const ushort* __restrict__ W, int rowbase) -> f32x16 {
    f32x16 a0 = zero16();
    #pragma unroll
    for (int dt = 0; dt < 16; ++dt)
      a0 = MFMA32(ldMnT(dt), ldG8(W, rowbase + l31, dt*16 + hl*8), a0);
    return a0;
  };
  auto packB = [&](const f32x16& q, bf16x8& lo, bf16x8& hi2) {
    lo  = mergeOp(q[0], q[1], q[2],  q[3],  q[4],  q[5],  q[6],  q[7]);
    hi2 = mergeOp(q[8], q[9], q[10], q[11], q[12], q[13], q[14], q[15]);
  };

  // ---------- prologue: K, then V (never co-live), then Q ----------
  bf16x8 bq0, bq1;
  {
    f32x16 KA = projT(qkv_wT, 256 + hs);
    #pragma unroll
    for (int rq = 0; rq < 4; ++rq) {
      uint2 p2;
      p2.x = pk2(KA[4*rq],   KA[4*rq+1]);
      p2.y = pk2(KA[4*rq+2], KA[4*rq+3]);
      *(uint2*)(smem + KOFF + s*80 + rq*16 + hl*8) = p2;
    }
  }
  {
    f32x16 VA = projN(qkv_wT, 512 + hs);
    #pragma unroll
    for (int rq = 0; rq < 4; ++rq) {
      uint2 p2;
      p2.x = pk2(VA[4*rq],   VA[4*rq+1]);
      p2.y = pk2(VA[4*rq+2], VA[4*rq+3]);
      *(uint2*)(smem + VOFF + l31*528 + Q0*2 + rq*16 + hl*8) = p2;
    }
  }
  {
    f32x16 QA = projT(qkv_wT, hs);
    packB(QA, bq0, bq1);
  }
  __syncthreads();

  // ---- flash loop: QK^T + direct 2^S + PV (O^T: col = q = l31), single O ----
  float lp0 = 0.f, lp1 = 0.f;
  f32x16 O = zero16();
  #pragma unroll
  for (int kt = 0; kt < 8; ++kt) {
    const bf16x8 a0 = *(const bf16x8*)(smem + KOFF + (kt*32 + l31)*80 + hl*16);
    const bf16x8 a1 = *(const bf16x8*)(smem + KOFF + (kt*32 + l31)*80 + 32 + hl*16);
    f32x16 S = MFMA32(a0, bq0, zero16());
    S = MFMA32(a1, bq1, S);

    #pragma unroll
    for (int i = 0; i < 16; ++i) {
      float p = exp2fast(S[i]);
      if (!full) {
        const int bi = kt*16 + i;
        const uint mw = (bi < 32) ? m0 : (bi < 64) ? m1 : (bi < 96) ? m2 : m3;
        p = ((mw >> (bi & 31)) & 1u) ? p : 0.f;
      }
      S[i] = p;
      if (i & 1) lp1 += p; else lp0 += p;
    }

    const bf16x8 pa0 = mergeOp(S[0], S[1], S[2],  S[3],  S[4],  S[5],  S[6],  S[7]);
    const bf16x8 vb0 = *(const bf16x8*)(smem + VOFF + l31*528 + kt*64 + hl*16);
    O = MFMA32(vb0, pa0, O);
    const bf16x8 pa1 = mergeOp(S[8], S[9], S[10], S[11], S[12], S[13], S[14], S[15]);
    const bf16x8 vb1 = *(const bf16x8*)(smem + VOFF + l31*528 + kt*64 + 32 + hl*16);
    O = MFMA32(vb1, pa1, O);
  }
  float l_ = lp0 + lp1;
  l_ += __shfl_xor(l_, 32, 64);
  const float inv = 1.0f / l_;   // per q = l31 = O column

  // ---- gate^T (projT: rows c-local, col q=l31 — same layout as O^T) ----
  f32x16 G = projT(gate_wT, hs);
  const int sxor = (s >> 1) & 15;
  #pragma unroll
  for (int ep = 0; ep < 8; ++ep) {
    const int e0 = 2*ep;
    const int c0 = (e0 & 3) + 8*(e0 >> 2) + 4*hl;     // c-local of reg e0
    const float g0 = gate_b[hs + c0];
    const float g1 = gate_b[hs + c0 + 1];
    const float v0 = O[e0]   * inv / (1.f + __expf(-(G[e0]   + g0)));
    const float v1 = O[e0+1] * inv / (1.f + __expf(-(G[e0+1] + g1)));
    const int cpair = (ep & 1) + 4*(ep >> 1) + 2*hl;  // = c0>>1
    *(uint*)(smem + GOFF + s*64 + ((cpair ^ sxor) << 2)) = pk2(v0, v1);
  }

  __syncthreads();   // og visible

  // ---- og readback -> fully coalesced global store ----
  uint* ogw = (uint*)og;
  const size_t ob = (size_t)(r*8 + hd) * 4096;
  #pragma unroll
  for (int j = 0; j < 8; ++j) {
    const int lin  = j*512 + tid;
    const int srow = lin >> 4;
    const int cu   = lin & 15;
    const uint wv = *(const uint*)(smem + GOFF + srow*64 + ((cu ^ ((srow >> 1) & 15)) << 2));
    ogw[ob + (size_t)srow*16 + cu] = wv;
  }
}

// ---------------- k_out: out[s][r][d] = M_raw + og2 @ out_w + out_b ----------
// acc split into two halves of 8 -> ~half the accumulator liveness -> more waves.
__global__ __launch_bounds__(256, 6) void k_out(
    const ushort* __restrict__ og, const ushort* __restrict__ out_wT,
    const float* __restrict__ out_b, const float* __restrict__ M_raw,
    float* __restrict__ out)
{
  const int blk  = blockIdx.x;
  const int tid  = threadIdx.x;
  const int w    = tid >> 6;
  const int lane = tid & 63;
  const int l15  = lane & 15;
  const int g    = lane >> 4;
  const int row0 = blk * 64 + w * 16;
  const int r    = row0 >> 8;
  const int s0   = row0 & 255;

  const f32x4 Z = {0.f, 0.f, 0.f, 0.f};
  #pragma unroll
  for (int half = 0; half < 2; ++half) {
    f32x4 acc[8];
    #pragma unroll
    for (int nt = 0; nt < 8; ++nt) acc[nt] = Z;

    #pragma unroll
    for (int kk = 0; kk < 8; ++kk) {   // kk == head
      const bf16x8 a = *(const bf16x8*)(og + ((size_t)(r*8 + kk)*256 + s0 + l15)*32 + g*8);
      #pragma unroll
      for (int nt = 0; nt < 8; ++nt) {
        const bf16x8 b = ldG8(out_wT, (half*8 + nt)*16 + l15, kk*32 + g*8);
        acc[nt] = MFMA16(a, b, acc[nt]);
      }
    }

    #pragma unroll
    for (int nt = 0; nt < 8; ++nt) {
      const int d = (half*8 + nt)*16 + l15;
      const float ob = out_b[d];
      #pragma unroll
      for (int i = 0; i < 4; ++i) {
        const int ss = s0 + 4*g + i;
        const size_t idx = (size_t)ss * 65536 + (size_t)r * 256 + d;
        out[idx] = M_raw[idx] + acc[nt][i] + ob;
      }
    }
  }
}

extern "C" void kernel_launch(void* const* d_in, const int* in_sizes, int n_in,
                              void* d_out, int out_size, void* d_ws, size_t ws_size,
                              hipStream_t stream) {
  const float* M_raw  = (const float*)d_in[0];
  const float* M_mask = (const float*)d_in[1];
  const float* ln_w   = (const float*)d_in[2];
  const float* ln_b   = (const float*)d_in[3];
  const float* qkv_w  = (const float*)d_in[4];
  const float* gate_w = (const float*)d_in[5];
  const float* gate_b = (const float*)d_in[6];
  const float* out_w  = (const float*)d_in[7];
  const float* out_b  = (const float*)d_in[8];

  ushort* ws      = (ushort*)d_ws;
  ushort* qkv_wT  = ws;
  ushort* gate_wT = ws + 196608;
  ushort* out_wT  = ws + 262144;
  ushort* og      = ws + 327680;
  ushort* Mn      = ws + 17104896;
  uint*   mbits   = (uint*)(ws + 33882112);

  hipFuncSetAttribute(reinterpret_cast<const void*>(k_attn),
                      hipFuncAttributeMaxDynamicSharedMemorySize, 53760);

  hipLaunchKernelGGL(k_prep, dim3(81), dim3(256), 0, stream,
                     qkv_w, gate_w, out_w, M_mask, ws, mbits);
  hipLaunchKernelGGL(k_ln, dim3(256, 8), dim3(256), 0, stream, M_raw, ln_w, ln_b, Mn);
  hipLaunchKernelGGL(k_attn, dim3(2048), dim3(512), 53760, stream,
                     Mn, mbits, qkv_wT, gate_wT, gate_b, og);
  hipLaunchKernelGGL(k_out, dim3(1024), dim3(256), 0, stream,
                     og, out_wT, out_b, M_raw, (float*)d_out);
}

// Round 20
// 381.368 us; speedup vs baseline: 1.3873x; 1.3873x over previous
//
#include <hip/hip_runtime.h>
#include <hip/hip_bf16.h>

// MSAColumnAttention fused kernels for MI355X (gfx950).
// N_SEQ=256, N_RES=256, D=256, H=8, C=32.
//
// ws layout (ushort elements):
//   [0       .. 196608)   qkv_wT  [768][256] bf16 (q rows pre-scaled by C^-0.5*log2e)
//   [196608  .. 262144)   gate_wT [256][256] bf16
//   [262144  .. 327680)   out_wT  [256][256] bf16
//   [327680  .. 17104896) og2     [r][h][s][c] bf16  (o * gate, head-major)
//   [17104896.. 33882112) Mn      [r][dt16][s][16] bf16 tiled (LayerNorm output)
//   [33882112.. 33898496) mbits   [r][hl][4] uint  (precomputed mask bitfields)

typedef short bf16x8 __attribute__((ext_vector_type(8)));
typedef float f32x4  __attribute__((ext_vector_type(4)));
typedef float f32x16 __attribute__((ext_vector_type(16)));

union U8 { uint w[4]; bf16x8 v; ushort u[8]; };

__device__ __forceinline__ ushort f2bf(float f) {
  uint u = __float_as_uint(f);
  u = (u + 0x7fffu + ((u >> 16) & 1u)) >> 16;   // RNE
  return (ushort)u;
}

// packed bf16 convert via library intrinsic -> compiler emits v_cvt_pk_bf16_f32
__device__ __forceinline__ uint pk2(float lo, float hi) {
  union { __hip_bfloat162 h; uint u; } cv;
  cv.h = __float22bfloat162_rn(float2{lo, hi});
  return cv.u;
}

// 2^x via v_exp_f32 (gfx950 v_exp_f32 computes 2^S0)
__device__ __forceinline__ float exp2fast(float x) {
  return __builtin_amdgcn_exp2f(x);
}

__device__ __forceinline__ f32x16 MFMA32(bf16x8 a, bf16x8 b, f32x16 c) {
  return __builtin_amdgcn_mfma_f32_32x32x16_bf16(a, b, c, 0, 0, 0);
}
__device__ __forceinline__ f32x4 MFMA16(bf16x8 a, bf16x8 b, f32x4 c) {
  return __builtin_amdgcn_mfma_f32_16x16x32_bf16(a, b, c, 0, 0, 0);
}

__device__ __forceinline__ bf16x8 ldG8(const ushort* __restrict__ p, int row, int ko) {
  return *(const bf16x8*)(p + (size_t)row * 256 + ko);
}

__device__ __forceinline__ f32x16 zero16() {
  f32x16 z;
  #pragma unroll
  for (int i = 0; i < 16; ++i) z[i] = 0.f;
  return z;
}

// ---------------- k_prep: weight transposes + mask bitfields -----------------
__global__ __launch_bounds__(256) void k_prep(const float* __restrict__ qkv_w,
                                              const float* __restrict__ gate_w,
                                              const float* __restrict__ out_w,
                                              const float* __restrict__ M_mask,
                                              ushort* __restrict__ ws,
                                              uint* __restrict__ mbits) {
  const int b = blockIdx.x;
  const int tid = threadIdx.x;
  if (b == 80) {
    const int r = tid;
    #pragma unroll
    for (int hl = 0; hl < 2; ++hl)
      #pragma unroll
      for (int j = 0; j < 4; ++j) {
        uint m = 0;
        for (int bb = 0; bb < 32; ++bb) {
          const int k0 = j*64 + ((bb>>4)<<5) + (bb&3) + (((bb>>2)&3)<<3) + hl*4;
          m |= (M_mask[(size_t)k0*256 + r] > 0.5f ? 1u : 0u) << bb;
        }
        mbits[(r*2 + hl)*4 + j] = m;
      }
    return;
  }
  __shared__ ushort t[64][72];
  const float* src; ushort* dst; int C, r0, c0; bool scale_q = false;
  if (b < 48)      { src = qkv_w;  dst = ws;          C = 768; r0 = (b/12)*64;      c0 = (b%12)*64; scale_q = true; }
  else if (b < 64) { int bb = b-48; src = gate_w; dst = ws + 196608; C = 256; r0 = (bb>>2)*64; c0 = (bb&3)*64; }
  else             { int bb = b-64; src = out_w;  dst = ws + 262144; C = 256; r0 = (bb>>2)*64; c0 = (bb&3)*64; }
  const int cc = tid & 63, rb = tid >> 6;
  #pragma unroll
  for (int j = 0; j < 16; ++j) {
    const int rr = j*4 + rb;
    float v = src[(size_t)(r0+rr)*C + c0 + cc];
    if (scale_q && (c0+cc) < 256) v *= 0.25503468786609404f;  // C^-0.5 * log2(e)
    t[cc][rr] = f2bf(v);
  }
  __syncthreads();
  const int dd = (tid & 31)*2, cb = tid >> 5;
  #pragma unroll
  for (int j = 0; j < 8; ++j) {
    const int c2 = j*8 + cb;
    const uint wv = (uint)t[c2][dd] | ((uint)t[c2][dd+1] << 16);
    *(uint*)(dst + (size_t)(c0+c2)*256 + r0 + dd) = wv;
  }
}

// ---------------- k_ln: LayerNorm -> Mn[r][dt][s][16] bf16 (tiled) -----------
__global__ __launch_bounds__(256) void k_ln(const float* __restrict__ M_raw,
                                            const float* __restrict__ ln_w,
                                            const float* __restrict__ ln_b,
                                            ushort* __restrict__ Mn) {
  const int s    = blockIdx.x;
  const int rc   = blockIdx.y;
  const int w    = threadIdx.x >> 6;
  const int lane = threadIdx.x & 63;
  const float4 wv = *(const float4*)(ln_w + lane*4);
  const float4 bv = *(const float4*)(ln_b + lane*4);
  const int wofs = (((lane >> 2) << 8) + s) * 16 + (lane & 3) * 4;
  #pragma unroll
  for (int i = 0; i < 8; ++i) {
    const int r = rc*32 + i*4 + w;
    const float4 x = *(const float4*)(M_raw + (size_t)s*65536 + (size_t)r*256 + lane*4);
    float sum = x.x + x.y + x.z + x.w;
    float sq  = x.x*x.x + x.y*x.y + x.z*x.z + x.w*x.w;
    #pragma unroll
    for (int mk = 1; mk <= 32; mk <<= 1) {
      sum += __shfl_xor(sum, mk, 64);
      sq  += __shfl_xor(sq,  mk, 64);
    }
    const float mu = sum * 0.00390625f;
    const float rs = rsqrtf(sq * 0.00390625f - mu*mu + 1e-5f);
    uint2 p2;
    p2.x = pk2((x.x-mu)*rs*wv.x+bv.x, (x.y-mu)*rs*wv.y+bv.y);
    p2.y = pk2((x.z-mu)*rs*wv.z+bv.z, (x.w-mu)*rs*wv.w+bv.w);
    *(uint2*)(Mn + (size_t)r*65536 + wofs) = p2;
  }
}

// ---------------- k_attn: one (r, head) per block, XCD-paired ----------------
// grid flat 2048: r = (bid>>6)*8 + (bid&7), h = (bid>>3)&7.
// (512,4): 128-reg budget, no spill (r18-proven) -> 2 blocks/CU, ~45% occupancy.
// LDS (dynamic, 53760B):
//   K  [0,20480):      K[s 256][c 32] bf16, pitch 80B
//   VT [20480,37376):  VT[c 32][s 256] bf16, pitch 528B
//   OG [37376,53760):  og [s 256][cpair 16] uint, XOR swz
#define KOFF 0
#define VOFF 20480
#define GOFF 37376

__global__ __launch_bounds__(512, 4) void k_attn(
    const ushort* __restrict__ Mn, const uint* __restrict__ mbits,
    const ushort* __restrict__ qkv_wT, const ushort* __restrict__ gate_wT,
    const float* __restrict__ gate_b, ushort* __restrict__ og)
{
  extern __shared__ char smem[];
  const int bid  = blockIdx.x;
  const int r    = ((bid >> 6) << 3) | (bid & 7);
  const int hd   = (bid >> 3) & 7;
  const int hs   = hd << 5;
  const int tid  = threadIdx.x;
  const int w    = tid >> 6;
  const int lane = tid & 63;
  const int l31  = lane & 31;
  const int hl   = lane >> 5;          // half-wave 0/1
  const int Q0   = w << 5;             // this wave's 32 s-rows
  const int s    = Q0 + l31;           // this lane's s-row (= its q column)
  const ushort* __restrict__ MnR = Mn + (size_t)r * 65536;

  auto ldMnT = [&](int dt) -> bf16x8 {
    return *(const bf16x8*)(MnR + ((dt << 8) + s) * 16 + hl * 8);
  };

  const uint4 mw4 = *(const uint4*)(mbits + (r*2 + hl)*4);
  const uint m0 = mw4.x, m1 = mw4.y, m2 = mw4.z, m3 = mw4.w;
  const bool full = ((m0 & m1 & m2 & m3) == 0xFFFFFFFFu);

  // C-frag (col=l31) -> A/B operand frag via shfl_xor 32 + select (proven r6..r18)
  auto mergeOp = [&](float q0, float q1, float q2, float q3,
                     float q4, float q5, float q6, float q7) -> bf16x8 {
    const uint x0 = pk2(q0, q1), x1 = pk2(q2, q3);
    const uint z0 = pk2(q4, q5), z1 = pk2(q6, q7);
    const uint xx0 = __shfl_xor(x0, 32, 64), xx1 = __shfl_xor(x1, 32, 64);
    const uint zz0 = __shfl_xor(z0, 32, 64), zz1 = __shfl_xor(z1, 32, 64);
    U8 u;
    u.w[0] = hl ? zz0 : x0;
    u.w[1] = hl ? zz1 : x1;
    u.w[2] = hl ? z0  : xx0;
    u.w[3] = hl ? z1  : xx1;
    return u.v;
  };

  // projT: C[row=c-local][col=s=l31] = W^T @ Mn^T   (single acc: min liveness)
  auto projT = [&](const ushort* __restrict__ W, int rowbase) -> f32x16 {
    f32x16 a0 = zero16();
    #pragma unroll
    for (int dt = 0; dt < 16; ++dt)
      a0 = MFMA32(ldG8(W, rowbase + l31, dt*16 + hl*8), ldMnT(dt), a0);
    return a0;
  };
  // projN: C[row=s-local][col=c=l31] = Mn @ W   (single acc)
  auto projN = [&](const ushort* __restrict__ W, int rowbase) -> f32x16 {
    f32x16 a0 = zero16();
    #pragma unroll
    for (int dt = 0; dt < 16; ++dt)
      a0 = MFMA32(ldMnT(dt), ldG8(W, rowbase + l31, dt*16 + hl*8), a0);
    return a0;
  };
  auto packB = [&](const f32x16& q, bf16x8& lo, bf16x8& hi2) {
    lo  = mergeOp(q[0], q[1], q[2],  q[3],  q[4],  q[5],  q[6],  q[7]);
    hi2 = mergeOp(q[8], q[9], q[10], q[11], q[12], q[13], q[14], q[15]);
  };

  // ---------- prologue: K, then V (never co-live), then Q ----------
  bf16x8 bq0, bq1;
  {
    f32x16 KA = projT(qkv_wT, 256 + hs);
    #pragma unroll
    for (int rq = 0; rq < 4; ++rq) {
      uint2 p2;
      p2.x = pk2(KA[4*rq],   KA[4*rq+1]);
      p2.y = pk2(KA[4*rq+2], KA[4*rq+3]);
      *(uint2*)(smem + KOFF + s*80 + rq*16 + hl*8) = p2;
    }
  }
  {
    f32x16 VA = projN(qkv_wT, 512 + hs);
    #pragma unroll
    for (int rq = 0; rq < 4; ++rq) {
      uint2 p2;
      p2.x = pk2(VA[4*rq],   VA[4*rq+1]);
      p2.y = pk2(VA[4*rq+2], VA[4*rq+3]);
      *(uint2*)(smem + VOFF + l31*528 + Q0*2 + rq*16 + hl*8) = p2;
    }
  }
  {
    f32x16 QA = projT(qkv_wT, hs);
    packB(QA, bq0, bq1);
  }
  __syncthreads();

  // ---- flash loop: QK^T + direct 2^S + PV (O^T: col = q = l31), single O ----
  float lp0 = 0.f, lp1 = 0.f;
  f32x16 O = zero16();
  #pragma unroll
  for (int kt = 0; kt < 8; ++kt) {
    const bf16x8 a0 = *(const bf16x8*)(smem + KOFF + (kt*32 + l31)*80 + hl*16);
    const bf16x8 a1 = *(const bf16x8*)(smem + KOFF + (kt*32 + l31)*80 + 32 + hl*16);
    f32x16 S = MFMA32(a0, bq0, zero16());
    S = MFMA32(a1, bq1, S);

    #pragma unroll
    for (int i = 0; i < 16; ++i) {
      float p = exp2fast(S[i]);
      if (!full) {
        const int bi = kt*16 + i;
        const uint mw = (bi < 32) ? m0 : (bi < 64) ? m1 : (bi < 96) ? m2 : m3;
        p = ((mw >> (bi & 31)) & 1u) ? p : 0.f;
      }
      S[i] = p;
      if (i & 1) lp1 += p; else lp0 += p;
    }

    const bf16x8 pa0 = mergeOp(S[0], S[1], S[2],  S[3],  S[4],  S[5],  S[6],  S[7]);
    const bf16x8 vb0 = *(const bf16x8*)(smem + VOFF + l31*528 + kt*64 + hl*16);
    O = MFMA32(vb0, pa0, O);
    const bf16x8 pa1 = mergeOp(S[8], S[9], S[10], S[11], S[12], S[13], S[14], S[15]);
    const bf16x8 vb1 = *(const bf16x8*)(smem + VOFF + l31*528 + kt*64 + 32 + hl*16);
    O = MFMA32(vb1, pa1, O);
  }
  float l_ = lp0 + lp1;
  l_ += __shfl_xor(l_, 32, 64);
  const float inv = 1.0f / l_;   // per q = l31 = O column

  // ---- gate^T (projT: rows c-local, col q=l31 — same layout as O^T) ----
  f32x16 G = projT(gate_wT, hs);
  const int sxor = (s >> 1) & 15;
  #pragma unroll
  for (int ep = 0; ep < 8; ++ep) {
    const int e0 = 2*ep;
    const int c0 = (e0 & 3) + 8*(e0 >> 2) + 4*hl;     // c-local of reg e0
    const float g0 = gate_b[hs + c0];
    const float g1 = gate_b[hs + c0 + 1];
    const float v0 = O[e0]   * inv / (1.f + __expf(-(G[e0]   + g0)));
    const float v1 = O[e0+1] * inv / (1.f + __expf(-(G[e0+1] + g1)));
    const int cpair = (ep & 1) + 4*(ep >> 1) + 2*hl;  // = c0>>1
    *(uint*)(smem + GOFF + s*64 + ((cpair ^ sxor) << 2)) = pk2(v0, v1);
  }

  __syncthreads();   // og visible

  // ---- og readback -> fully coalesced global store ----
  uint* ogw = (uint*)og;
  const size_t ob = (size_t)(r*8 + hd) * 4096;
  #pragma unroll
  for (int j = 0; j < 8; ++j) {
    const int lin  = j*512 + tid;
    const int srow = lin >> 4;
    const int cu   = lin & 15;
    const uint wv = *(const uint*)(smem + GOFF + srow*64 + ((cu ^ ((srow >> 1) & 15)) << 2));
    ogw[ob + (size_t)srow*16 + cu] = wv;
  }
}

// ---------------- k_out: out[s][r][d] = M_raw + og2 @ out_w + out_b ----------
// acc split into two halves of 8 -> half the accumulator liveness; safe (256,4).
__global__ __launch_bounds__(256, 4) void k_out(
    const ushort* __restrict__ og, const ushort* __restrict__ out_wT,
    const float* __restrict__ out_b, const float* __restrict__ M_raw,
    float* __restrict__ out)
{
  const int blk  = blockIdx.x;
  const int tid  = threadIdx.x;
  const int w    = tid >> 6;
  const int lane = tid & 63;
  const int l15  = lane & 15;
  const int g    = lane >> 4;
  const int row0 = blk * 64 + w * 16;
  const int r    = row0 >> 8;
  const int s0   = row0 & 255;

  const f32x4 Z = {0.f, 0.f, 0.f, 0.f};
  #pragma unroll
  for (int half = 0; half < 2; ++half) {
    f32x4 acc[8];
    #pragma unroll
    for (int nt = 0; nt < 8; ++nt) acc[nt] = Z;

    #pragma unroll
    for (int kk = 0; kk < 8; ++kk) {   // kk == head
      const bf16x8 a = *(const bf16x8*)(og + ((size_t)(r*8 + kk)*256 + s0 + l15)*32 + g*8);
      #pragma unroll
      for (int nt = 0; nt < 8; ++nt) {
        const bf16x8 b = ldG8(out_wT, (half*8 + nt)*16 + l15, kk*32 + g*8);
        acc[nt] = MFMA16(a, b, acc[nt]);
      }
    }

    #pragma unroll
    for (int nt = 0; nt < 8; ++nt) {
      const int d = (half*8 + nt)*16 + l15;
      const float ob = out_b[d];
      #pragma unroll
      for (int i = 0; i < 4; ++i) {
        const int ss = s0 + 4*g + i;
        const size_t idx = (size_t)ss * 65536 + (size_t)r * 256 + d;
        out[idx] = M_raw[idx] + acc[nt][i] + ob;
      }
    }
  }
}

extern "C" void kernel_launch(void* const* d_in, const int* in_sizes, int n_in,
                              void* d_out, int out_size, void* d_ws, size_t ws_size,
                              hipStream_t stream) {
  const float* M_raw  = (const float*)d_in[0];
  const float* M_mask = (const float*)d_in[1];
  const float* ln_w   = (const float*)d_in[2];
  const float* ln_b   = (const float*)d_in[3];
  const float* qkv_w  = (const float*)d_in[4];
  const float* gate_w = (const float*)d_in[5];
  const float* gate_b = (const float*)d_in[6];
  const float* out_w  = (const float*)d_in[7];
  const float* out_b  = (const float*)d_in[8];

  ushort* ws      = (ushort*)d_ws;
  ushort* qkv_wT  = ws;
  ushort* gate_wT = ws + 196608;
  ushort* out_wT  = ws + 262144;
  ushort* og      = ws + 327680;
  ushort* Mn      = ws + 17104896;
  uint*   mbits   = (uint*)(ws + 33882112);

  hipFuncSetAttribute(reinterpret_cast<const void*>(k_attn),
                      hipFuncAttributeMaxDynamicSharedMemorySize, 53760);

  hipLaunchKernelGGL(k_prep, dim3(81), dim3(256), 0, stream,
                     qkv_w, gate_w, out_w, M_mask, ws, mbits);
  hipLaunchKernelGGL(k_ln, dim3(256, 8), dim3(256), 0, stream, M_raw, ln_w, ln_b, Mn);
  hipLaunchKernelGGL(k_attn, dim3(2048), dim3(512), 53760, stream,
                     Mn, mbits, qkv_wT, gate_wT, gate_b, og);
  hipLaunchKernelGGL(k_out, dim3(1024), dim3(256), 0, stream,
                     og, out_wT, out_b, M_raw, (float*)d_out);
}